// Round 2
// baseline (126.004 us; speedup 1.0000x reference)
//
#include <hip/hip_runtime.h>

#define F_SCALE 0.02581988897471611f   // 1/sqrt(1500)
#define F_LOG2E 1.4426950408889634f

constexpr int B_ = 32;
constexpr int L_ = 1500;

// A (float4) += s * e
#define ACC4(A, s, e) \
    A.x = fmaf(s, e.x, A.x); A.y = fmaf(s, e.y, A.y); \
    A.z = fmaf(s, e.z, A.z); A.w = fmaf(s, e.w, A.w)

// ---------------------------------------------------------------------------
// Grid (4, 32): xs = conv2 time-quarter (23 of 92 cols), b = batch.
// Each block: full moment matrix G (redundant x4, cheap & verified), then
// only its slice of T (388 vals), h1 (96 cols), h2 (64 x 23 -> global).
// Second kernel does conv3+logit per batch (needs all h2 channels/cols).
// Window algebra: h2 col t in [23xs, 23xs+23) reads h1 cols 4t..4t+7
//   -> h1 cols [92xs, 92xs+95] (96 cols, local c=0..95)
//   -> h1 col (92xs+c) reads T[368xs + 4c .. +7] -> TD local idx 0..387.
// ---------------------------------------------------------------------------
__global__ __launch_bounds__(512) void main_k(
    const float* __restrict__ signal,
    const float* __restrict__ wq, const float* __restrict__ bq,
    const float* __restrict__ wk,
    const float* __restrict__ wv, const float* __restrict__ bv,
    const float* __restrict__ w1, const float* __restrict__ b1,
    const float* __restrict__ w2, const float* __restrict__ b2,
    float* __restrict__ h2)
{
    __shared__ float  sw[1504];        // sig[-1..1502], zero-padded
    __shared__ float4 umq[3500];       // moment rows, pitch 7 (chunks of 500)
    __shared__ float  red[6400];       // strip-reduce scratch (5 grp x 64 x 20)
    __shared__ float4 Gs4[20];         // G moments (20 monomials x 4)
    __shared__ float4 TDs[392];        // T window (388 used)
    __shared__ float  h1s[32 * 100];   // h1 slice [32][96] pitch 100

    const int tid = threadIdx.x;
    const int xs  = blockIdx.x;        // 0..3
    const int b   = blockIdx.y;
    const int wid = tid >> 6;
    const int ln  = tid & 63;
    const float* sgb = signal + (size_t)b * L_;

    // ---- stage full signal window
    for (int i = tid; i < 1504; i += 512) {
        const int gi = i - 1;
        sw[i] = (gi >= 0 && gi < L_) ? sgb[gi] : 0.0f;
    }

    // ---- register-only weight folds (overlap staging latency)
    float Mm[9], uu[3];
    #pragma unroll
    for (int a = 0; a < 3; a++) {
        #pragma unroll
        for (int d = 0; d < 3; d++) {
            float acc = 0.0f;
            #pragma unroll
            for (int c = 0; c < 8; c++) acc += wq[c*3+a] * wk[c*3+d];
            Mm[a*3+d] = acc * F_SCALE;
        }
    }
    #pragma unroll
    for (int d = 0; d < 3; d++) {
        float acc = 0.0f;
        #pragma unroll
        for (int c = 0; c < 8; c++) acc += bq[c] * wk[c*3+d];
        uu[d] = acc * (F_SCALE * F_LOG2E);
    }
    // conv1 fold: per-o A[8][3], b1p (o = tid&31)
    const int o31 = tid & 31;
    float A[8][3];
    float b1p = b1[o31];
    #pragma unroll
    for (int k = 0; k < 8; ++k) { A[k][0]=0.f; A[k][1]=0.f; A[k][2]=0.f; }
    #pragma unroll
    for (int i = 0; i < 8; ++i) {
        const float v0 = wv[i*3+0], v1 = wv[i*3+1], v2 = wv[i*3+2];
        const float bvi = bv[i];
        #pragma unroll
        for (int k = 0; k < 8; ++k) {
            const float w = w1[o31*64 + i*8 + k];
            A[k][0] = fmaf(w, v0, A[k][0]);
            A[k][1] = fmaf(w, v1, A[k][1]);
            A[k][2] = fmaf(w, v2, A[k][2]);
            b1p     = fmaf(w, bvi, b1p);
        }
    }
    __syncthreads();

    // ---- phase A: moments (verbatim structure from verified kernel)
    float4 aq0 = make_float4(0,0,0,0), aq1 = aq0, aq2 = aq0, aq3 = aq0;
    for (int chk = 0; chk < 3; ++chk) {
        const int m0 = chk * 500;
        if (tid < 500) {
            const int j = tid;
            const float x0 = sw[m0+j], x1 = sw[m0+j+1], x2 = sw[m0+j+2];
            const float h0  = Mm[0]*x0 + Mm[1]*x1 + Mm[2]*x2;
            const float h1v = Mm[3]*x0 + Mm[4]*x1 + Mm[5]*x2;
            const float h2v = Mm[6]*x0 + Mm[7]*x1 + Mm[8]*x2;
            const float E   = __builtin_amdgcn_exp2f(uu[0]*x0 + uu[1]*x1 + uu[2]*x2);
            const float p00=h0*h0, p01=h0*h1v, p02=h0*h2v;
            const float p11=h1v*h1v, p12=h1v*h2v, p22=h2v*h2v;
            float4* row = &umq[j*7];
            row[0] = make_float4(E*x0, E*x1, E*x2, E);
            row[1] = make_float4(h0, h1v, h2v, p00);
            row[2] = make_float4(p01, p02, p11, p12);
            row[3] = make_float4(p22, h0*p00, h1v*p00, h2v*p00);
            row[4] = make_float4(h0*p11, h0*p12, h0*p22, h1v*p11);
            row[5] = make_float4(h2v*p11, h1v*p22, h2v*p22, 1.0f);
        }
        __syncthreads();
        if (wid < 5) {
            #pragma unroll
            for (int ii = 0; ii < 8; ++ii) {
                const int j = ln + 64*ii;
                if (j < 500) {
                    const float4 ex = umq[j*7];
                    const float4 mq = umq[j*7 + 1 + wid];
                    ACC4(aq0, mq.x, ex); ACC4(aq1, mq.y, ex);
                    ACC4(aq2, mq.z, ex); ACC4(aq3, mq.w, ex);
                }
            }
        }
        __syncthreads();
    }
    if (wid < 5) {
        float4* rp = (float4*)&red[(wid*64 + ln)*20];
        rp[0] = aq0; rp[1] = aq1; rp[2] = aq2; rp[3] = aq3;
    }
    __syncthreads();
    if (tid < 80) {
        const int jm = tid >> 2, cc = tid & 3;
        int grp, qq;
        if (jm == 0)      { grp = 4; qq = 3; }
        else if (jm < 17) { grp = (jm-1) >> 2; qq = (jm-1) & 3; }
        else              { grp = 4; qq = jm - 17; }
        const float* rb = red + (size_t)grp*64*20 + qq*4 + cc;
        float val = 0.0f;
        #pragma unroll 8
        for (int l = 0; l < 64; ++l) val += rb[l*20];
        ((float*)Gs4)[tid] = val;
    }
    __syncthreads();

    // ---- phase T: this block's window only (l = 368*xs + t, t < 388)
    if (tid < 388) {
        const int l = 368*xs + tid;
        const float y0 = sw[l], y1 = sw[l+1], y2 = sw[l+2];
        const float t00=y0*y0, t01=y0*y1, t02=y0*y2, t11=y1*y1, t12=y1*y2, t22=y2*y2;
        const float c6 = 1.0f/6.0f;
        float ym[20];
        ym[0]=1.0f; ym[1]=y0; ym[2]=y1; ym[3]=y2;
        ym[4]=0.5f*t00; ym[5]=t01; ym[6]=t02; ym[7]=0.5f*t11; ym[8]=t12; ym[9]=0.5f*t22;
        ym[10]=c6*(y0*t00);  ym[11]=0.5f*(y1*t00); ym[12]=0.5f*(y2*t00);
        ym[13]=0.5f*(y0*t11); ym[14]=y0*t12;       ym[15]=0.5f*(y0*t22);
        ym[16]=c6*(y1*t11);  ym[17]=0.5f*(y2*t11); ym[18]=0.5f*(y1*t22);
        ym[19]=c6*(y2*t22);
        float4 S = make_float4(0,0,0,0);
        #pragma unroll
        for (int jj = 0; jj < 20; ++jj) {
            const float4 G = Gs4[jj];          // uniform b128 broadcast
            ACC4(S, ym[jj], G);
        }
        const float rd = 1.0f / S.w;
        TDs[tid] = make_float4(S.x*rd, S.y*rd, S.z*rd, 0.0f);
    }
    __syncthreads();

    // ---- conv1: h1 slice, 96 cols (o = tid&31, cols cg, cg+16, ...)
    {
        const int cg = tid >> 5;
        for (int c = cg; c < 96; c += 16) {
            float acc = b1p;
            #pragma unroll
            for (int k = 0; k < 8; ++k) {
                const float4 T = TDs[4*c + k];  // half-wave uniform broadcast
                acc += A[k][0]*T.x + A[k][1]*T.y + A[k][2]*T.z;
            }
            h1s[o31*100 + c] = acc;
        }
    }
    __syncthreads();

    // ---- conv2: 23 cols x 64 o; thread = (op 0..15, ts 0..31), 4 o each
    {
        const int op = tid >> 5;
        const int ts = tid & 31;
        if (ts < 23) {
            float acc[4];
            #pragma unroll
            for (int q = 0; q < 4; ++q) acc[q] = b2[op + 16*q];
            const float4* w2q4 = (const float4*)w2;
            const float4* h1s4 = (const float4*)h1s;    // pitch 25 float4
            #pragma unroll 4
            for (int i = 0; i < 32; ++i) {
                const float4 a0 = h1s4[i*25 + ts];
                const float4 a1 = h1s4[i*25 + ts + 1];
                #pragma unroll
                for (int q = 0; q < 4; ++q) {
                    const float4 wA = w2q4[(op+16*q)*64 + 2*i];   // half-wave uniform
                    const float4 wB = w2q4[(op+16*q)*64 + 2*i + 1];
                    acc[q] += a0.x*wA.x + a0.y*wA.y + a0.z*wA.z + a0.w*wA.w
                            + a1.x*wB.x + a1.y*wB.y + a1.z*wB.z + a1.w*wB.w;
                }
            }
            #pragma unroll
            for (int q = 0; q < 4; ++q)
                h2[((size_t)b*64 + op + 16*q)*96 + 23*xs + ts] = acc[q];
        }
    }
}

// h3 (8x22 per batch) + logit Linear(176,3), fused per batch through LDS
__global__ __launch_bounds__(192) void conv3_logit(
    const float* __restrict__ h2, const float* __restrict__ w3,
    const float* __restrict__ b3, const float* __restrict__ wl,
    const float* __restrict__ bl, float* __restrict__ out)
{
    __shared__ float flat[176];
    const int tid = threadIdx.x, b = blockIdx.x;
    if (tid < 176) {
        const int c = tid / 22, t = tid % 22;   // flat = h3.reshape: c*22 + t
        float acc = b3[c];
        const float4* hb = reinterpret_cast<const float4*>(h2 + (size_t)b * 64 * 96);
        #pragma unroll 8
        for (int i = 0; i < 64; i++) {
            const float4 a0 = hb[i * 24 + t];
            const float4 a1 = hb[i * 24 + t + 1];
            const float* w = w3 + (c * 64 + i) * 8;
            acc += a0.x*w[0] + a0.y*w[1] + a0.z*w[2] + a0.w*w[3]
                 + a1.x*w[4] + a1.y*w[5] + a1.z*w[6] + a1.w*w[7];
        }
        flat[tid] = acc;
    }
    __syncthreads();
    if (tid < 3) {
        float acc = bl[tid];
        for (int n = 0; n < 176; n++) acc += flat[n] * wl[tid * 176 + n];
        out[b * 3 + tid] = acc;
    }
}

extern "C" void kernel_launch(void* const* d_in, const int* in_sizes, int n_in,
                              void* d_out, int out_size, void* d_ws, size_t ws_size,
                              hipStream_t stream) {
    const float* signal = (const float*)d_in[0];
    const float* wq = (const float*)d_in[1];  const float* bq = (const float*)d_in[2];
    const float* wk = (const float*)d_in[3];  /* bk cancels in softmax */
    const float* wv = (const float*)d_in[5];  const float* bv = (const float*)d_in[6];
    const float* w1 = (const float*)d_in[7];  const float* b1 = (const float*)d_in[8];
    const float* w2 = (const float*)d_in[9];  const float* b2 = (const float*)d_in[10];
    const float* w3 = (const float*)d_in[11]; const float* b3 = (const float*)d_in[12];
    const float* wl = (const float*)d_in[13]; const float* bl = (const float*)d_in[14];
    float* out = (float*)d_out;

    float* h2 = (float*)d_ws;                 // [32][64][96]

    hipLaunchKernelGGL(main_k, dim3(4, 32), dim3(512), 0, stream,
                       signal, wq, bq, wk, wv, bv, w1, b1, w2, b2, h2);
    hipLaunchKernelGGL(conv3_logit, dim3(32), dim3(192), 0, stream,
                       h2, w3, b3, wl, bl, out);
}

// Round 3
// 117.037 us; speedup vs baseline: 1.0766x; 1.0766x over previous
//
#include <hip/hip_runtime.h>

#define F_SCALE 0.02581988897471611f   // 1/sqrt(1500)
#define F_LOG2E 1.4426950408889634f

constexpr int B_ = 32;
constexpr int L_ = 1500;
constexpr int MS_ = 4;        // m-splits for moment reduction
constexpr int MC_ = 375;      // 1500/4 exact
constexpr int NMONO = 20;     // monomials of degree<=3 in 3 vars
constexpr int NG = 80;        // NMONO * 4 (x0,x1,x2,1)

// workspace layout (floats): ps [32][4][80], h2 [32][64][96]
constexpr size_t OFF_PS = 0;
constexpr size_t SZ_PS  = (size_t)B_ * MS_ * NG;
constexpr size_t OFF_H2 = OFF_PS + SZ_PS;   // 10240

// A (float4) += s * e
#define ACC4(A, s, e) \
    A.x = fmaf(s, e.x, A.x); A.y = fmaf(s, e.y, A.y); \
    A.z = fmaf(s, e.z, A.z); A.w = fmaf(s, e.w, A.w)

// ---------------------------------------------------------------------------
// K1: attention collapsed to moments (verified round-0 kernel, verbatim).
// Each block reduces its own 375 m's -> partial G (80 floats) to ps.
// ---------------------------------------------------------------------------
__global__ __launch_bounds__(256) void attn_moments(
    const float* __restrict__ signal,
    const float* __restrict__ wq, const float* __restrict__ bq,
    const float* __restrict__ wk,
    float* __restrict__ ps)
{
    __shared__ float sw[MC_ + 2];     // sig[m0-1 .. m0+MC_]
    __shared__ float um[MC_ * 24];    // per m: [0..3]=E*x0,E*x1,E*x2,E; [4..22]=mono; [23]=1
    __shared__ float part[240];

    const int tid = threadIdx.x;
    const int ms  = blockIdx.x;
    const int b   = blockIdx.y;
    const int m0  = ms * MC_;

    const float* sgb = signal + (size_t)b * L_;
    for (int i = tid; i < MC_ + 2; i += 256) {
        const int gi = m0 + i - 1;
        sw[i] = (gi >= 0 && gi < L_) ? sgb[gi] : 0.0f;
    }

    // M' = Wq^T Wk * SCALE (natural units); uu = Wk^T bq * SCALE * LOG2E
    float Mm[9], uu[3];
    #pragma unroll
    for (int a = 0; a < 3; a++) {
        #pragma unroll
        for (int d = 0; d < 3; d++) {
            float acc = 0.0f;
            #pragma unroll
            for (int c = 0; c < 8; c++) acc += wq[c*3+a] * wk[c*3+d];
            Mm[a*3+d] = acc * F_SCALE;
        }
    }
    #pragma unroll
    for (int d = 0; d < 3; d++) {
        float acc = 0.0f;
        #pragma unroll
        for (int c = 0; c < 8; c++) acc += bq[c] * wk[c*3+d];
        uu[d] = acc * (F_SCALE * F_LOG2E);
    }
    __syncthreads();

    // phase 1: per-m monomial rows
    for (int j = tid; j < MC_; j += 256) {
        const float x0 = sw[j], x1 = sw[j+1], x2 = sw[j+2];
        const float h0 = Mm[0]*x0 + Mm[1]*x1 + Mm[2]*x2;
        const float h1 = Mm[3]*x0 + Mm[4]*x1 + Mm[5]*x2;
        const float h2 = Mm[6]*x0 + Mm[7]*x1 + Mm[8]*x2;
        const float E  = __builtin_amdgcn_exp2f(uu[0]*x0 + uu[1]*x1 + uu[2]*x2);
        float* row = &um[j*24];
        row[0]=E*x0; row[1]=E*x1; row[2]=E*x2; row[3]=E;
        row[4]=h0; row[5]=h1; row[6]=h2;
        const float p00=h0*h0, p01=h0*h1, p02=h0*h2, p11=h1*h1, p12=h1*h2, p22=h2*h2;
        row[7]=p00;  row[8]=p01;  row[9]=p02;  row[10]=p11; row[11]=p12; row[12]=p22;
        row[13]=h0*p00; row[14]=h1*p00; row[15]=h2*p00;
        row[16]=h0*p11; row[17]=h0*p12; row[18]=h0*p22;
        row[19]=h1*p11; row[20]=h2*p11; row[21]=h1*p22; row[22]=h2*p22;
        row[23]=1.0f;
    }
    __syncthreads();

    // phase 2: 3 groups x 80 (mono,c) pairs reduce 125 m's each
    if (tid < 240) {
        const int g = tid / 80, p = tid - g * 80;
        const int c = p & 3, jm = p >> 2;
        const int off = (jm == 0) ? 23 : (3 + jm);
        const int j1 = (g + 1) * 125;
        float acc = 0.0f;
        #pragma unroll 5
        for (int j = g * 125; j < j1; j++)
            acc = fmaf(um[j*24 + off], um[j*24 + c], acc);
        part[tid] = acc;
    }
    __syncthreads();
    if (tid < 80)
        ps[((size_t)b * MS_ + ms) * NG + tid] =
            part[tid] + part[80 + tid] + part[160 + tid];
}

// ---------------------------------------------------------------------------
// K2: G-combine + T-window + conv1 + conv2 for one (xs, b) quarter.
// Window algebra (verified round 2): h2 col t in [23xs, 23xs+23) reads h1
// cols 4t..4t+7 -> h1 cols [92xs, 92xs+95] (local c=0..95); h1 col (92xs+c)
// reads T global l = 368xs + 4c..+7 -> local TD idx 0..387.
// w2 staged in LDS (pitch 260 floats -> o and o+8 differ by 4 banks ->
// conflict-free 8-lane-broadcast b128 reads).
// ---------------------------------------------------------------------------
__global__ __launch_bounds__(512) void ctx_conv12(
    const float* __restrict__ signal,
    const float* __restrict__ ps,
    const float* __restrict__ wv, const float* __restrict__ bv,
    const float* __restrict__ w1, const float* __restrict__ b1,
    const float* __restrict__ w2, const float* __restrict__ b2,
    float* __restrict__ h2)
{
    __shared__ float4 Gs4[NMONO];
    __shared__ float  swl[392];        // sig window [l0-1 .. l0+388]
    __shared__ float4 TDs[388];
    __shared__ float  h1s[32 * 100];   // h1 slice [32][96] pitch 100
    __shared__ float  w2s[64 * 260];   // w2 rows, pitch 260 floats

    const int tid = threadIdx.x;
    const int xs  = blockIdx.x;        // 0..3
    const int b   = blockIdx.y;
    const int l0  = 368 * xs;

    // stage w2 -> LDS (coalesced global float4)
    {
        const float4* w2g = (const float4*)w2;
        for (int idx = tid; idx < 64 * 64; idx += 512) {
            const int o = idx >> 6, q = idx & 63;
            *(float4*)&w2s[o * 260 + 4 * q] = w2g[idx];
        }
    }
    // stage signal window: swl[i] = sig[l0 + i - 1], i in [0, 390)
    const float* sgb = signal + (size_t)b * L_;
    for (int i = tid; i < 390; i += 512) {
        const int gi = l0 + i - 1;
        swl[i] = (gi >= 0 && gi < L_) ? sgb[gi] : 0.0f;
    }
    // combine 4 partial G's (same order as verified round-0 kernel)
    if (tid < NG) {
        const float* pb = ps + (size_t)b * MS_ * NG + tid;
        ((float*)Gs4)[tid] = pb[0] + pb[NG] + pb[2*NG] + pb[3*NG];
    }

    // conv1 fold: per-o A[8][3], b1p (o = tid&31) — register-only
    const int o31 = tid & 31;
    float A[8][3];
    float b1p = b1[o31];
    #pragma unroll
    for (int k = 0; k < 8; ++k) { A[k][0]=0.f; A[k][1]=0.f; A[k][2]=0.f; }
    #pragma unroll
    for (int i = 0; i < 8; ++i) {
        const float v0 = wv[i*3+0], v1 = wv[i*3+1], v2 = wv[i*3+2];
        const float bvi = bv[i];
        #pragma unroll
        for (int k = 0; k < 8; ++k) {
            const float w = w1[o31*64 + i*8 + k];
            A[k][0] = fmaf(w, v0, A[k][0]);
            A[k][1] = fmaf(w, v1, A[k][1]);
            A[k][2] = fmaf(w, v2, A[k][2]);
            b1p     = fmaf(w, bvi, b1p);
        }
    }
    __syncthreads();

    // T window: t in [0,388), global l = l0 + t
    if (tid < 388) {
        const float y0 = swl[tid], y1 = swl[tid+1], y2 = swl[tid+2];
        const float t00=y0*y0, t01=y0*y1, t02=y0*y2, t11=y1*y1, t12=y1*y2, t22=y2*y2;
        const float c6 = 1.0f/6.0f;
        float ym[NMONO];
        ym[0]=1.0f; ym[1]=y0; ym[2]=y1; ym[3]=y2;
        ym[4]=0.5f*t00; ym[5]=t01; ym[6]=t02; ym[7]=0.5f*t11; ym[8]=t12; ym[9]=0.5f*t22;
        ym[10]=c6*(y0*t00);  ym[11]=0.5f*(y1*t00); ym[12]=0.5f*(y2*t00);
        ym[13]=0.5f*(y0*t11); ym[14]=y0*t12;       ym[15]=0.5f*(y0*t22);
        ym[16]=c6*(y1*t11);  ym[17]=0.5f*(y2*t11); ym[18]=0.5f*(y1*t22);
        ym[19]=c6*(y2*t22);
        float4 S = make_float4(0.f, 0.f, 0.f, 0.f);
        #pragma unroll
        for (int jj = 0; jj < NMONO; ++jj) {
            const float4 G = Gs4[jj];          // uniform b128 broadcast
            ACC4(S, ym[jj], G);
        }
        const float rd = 1.0f / S.w;
        TDs[tid] = make_float4(S.x*rd, S.y*rd, S.z*rd, 0.0f);
    }
    __syncthreads();

    // conv1: 96 cols (o = tid&31, cols cg, cg+16, ...)
    {
        const int cg = tid >> 5;
        for (int c = cg; c < 96; c += 16) {
            float acc = b1p;
            #pragma unroll
            for (int k = 0; k < 8; ++k) {
                const float4 T = TDs[4*c + k];  // half-wave uniform broadcast
                acc += A[k][0]*T.x + A[k][1]*T.y + A[k][2]*T.z;
            }
            h1s[o31*100 + c] = acc;
        }
    }
    __syncthreads();

    // conv2: thread = (o = tid>>3, slot s = tid&7), 3 t-cols each (t<23)
    {
        const int o = tid >> 3, s = tid & 7;
        const int t0 = 3 * s;
        const float bo = b2[o];
        float acc0 = bo, acc1 = bo, acc2 = bo;
        const float4* h1s4 = (const float4*)h1s;            // pitch 25
        const float4* wrow = (const float4*)&w2s[o * 260];  // 260%4==0 -> aligned
        #pragma unroll 4
        for (int i = 0; i < 32; ++i) {
            const float4 wA = wrow[2*i], wB = wrow[2*i + 1];
            const float4 a0 = h1s4[i*25 + t0];
            const float4 a1 = h1s4[i*25 + t0 + 1];
            const float4 a2 = h1s4[i*25 + t0 + 2];
            const float4 a3 = h1s4[i*25 + t0 + 3];
            acc0 += a0.x*wA.x + a0.y*wA.y + a0.z*wA.z + a0.w*wA.w
                  + a1.x*wB.x + a1.y*wB.y + a1.z*wB.z + a1.w*wB.w;
            acc1 += a1.x*wA.x + a1.y*wA.y + a1.z*wA.z + a1.w*wA.w
                  + a2.x*wB.x + a2.y*wB.y + a2.z*wB.z + a2.w*wB.w;
            acc2 += a2.x*wA.x + a2.y*wA.y + a2.z*wA.z + a2.w*wA.w
                  + a3.x*wB.x + a3.y*wB.y + a3.z*wB.z + a3.w*wB.w;
        }
        float* hb = h2 + ((size_t)b * 64 + o) * 96 + 23 * xs;
        if (t0     < 23) hb[t0]     = acc0;
        if (t0 + 1 < 23) hb[t0 + 1] = acc1;
        if (t0 + 2 < 23) hb[t0 + 2] = acc2;
    }
}

// K3: h3 (8x22 per batch) + logit Linear(176,3), fused per batch (verbatim)
__global__ __launch_bounds__(192) void conv3_logit(
    const float* __restrict__ h2, const float* __restrict__ w3,
    const float* __restrict__ b3, const float* __restrict__ wl,
    const float* __restrict__ bl, float* __restrict__ out)
{
    __shared__ float flat[176];
    const int tid = threadIdx.x, b = blockIdx.x;
    if (tid < 176) {
        const int c = tid / 22, t = tid % 22;   // flat = h3.reshape: c*22 + t
        float acc = b3[c];
        const float4* hb = reinterpret_cast<const float4*>(h2 + (size_t)b * 64 * 96);
        #pragma unroll 8
        for (int i = 0; i < 64; i++) {
            const float4 a0 = hb[i * 24 + t];
            const float4 a1 = hb[i * 24 + t + 1];
            const float* w = w3 + (c * 64 + i) * 8;
            acc += a0.x*w[0] + a0.y*w[1] + a0.z*w[2] + a0.w*w[3]
                 + a1.x*w[4] + a1.y*w[5] + a1.z*w[6] + a1.w*w[7];
        }
        flat[tid] = acc;
    }
    __syncthreads();
    if (tid < 3) {
        float acc = bl[tid];
        for (int n = 0; n < 176; n++) acc += flat[n] * wl[tid * 176 + n];
        out[b * 3 + tid] = acc;
    }
}

extern "C" void kernel_launch(void* const* d_in, const int* in_sizes, int n_in,
                              void* d_out, int out_size, void* d_ws, size_t ws_size,
                              hipStream_t stream) {
    const float* signal = (const float*)d_in[0];
    const float* wq = (const float*)d_in[1];  const float* bq = (const float*)d_in[2];
    const float* wk = (const float*)d_in[3];  /* bk cancels in softmax */
    const float* wv = (const float*)d_in[5];  const float* bv = (const float*)d_in[6];
    const float* w1 = (const float*)d_in[7];  const float* b1 = (const float*)d_in[8];
    const float* w2 = (const float*)d_in[9];  const float* b2 = (const float*)d_in[10];
    const float* w3 = (const float*)d_in[11]; const float* b3 = (const float*)d_in[12];
    const float* wl = (const float*)d_in[13]; const float* bl = (const float*)d_in[14];
    float* out = (float*)d_out;

    float* ws = (float*)d_ws;
    float* ps = ws + OFF_PS;                  // [32][4][80]
    float* h2 = ws + OFF_H2;                  // [32][64][96]

    hipLaunchKernelGGL(attn_moments, dim3(MS_, 32), dim3(256), 0, stream,
                       signal, wq, bq, wk, ps);
    hipLaunchKernelGGL(ctx_conv12, dim3(4, 32), dim3(512), 0, stream,
                       signal, ps, wv, bv, w1, b1, w2, b2, h2);
    hipLaunchKernelGGL(conv3_logit, dim3(32), dim3(192), 0, stream,
                       h2, w3, b3, wl, bl, out);
}